// Round 4
// baseline (68.362 us; speedup 1.0000x reference)
//
#include <hip/hip_runtime.h>
#include <math.h>

#define N_BINS 256
#define TAU 0.01f
#define EPS 1e-10f
#define HW (512*512)
#define Q 4081            // quant levels; Q-1 = 4080 = 16*255 so t_q - b_j = (q-16j)/4080
#define QSTRIDE 4096
#define MWIN 208          // |q-16j| <= 208 -> dropped weight exp(-13) ~ 2e-6 (negligible)
#define WTAB (2*MWIN+1)   // 417
#define WPADN 432         // 16*27, zero-padded tail
#define NP 27             // taps per phase: m = 16*(p-13)+r
#define CFP_STRIDE 289    // odd stride -> 2-way bank aliasing only (free)
#define NPART 64          // blocks per batch
#define BMAX 4
#define HSTRIDE 16        // one 64B line per bin: per-line atomic chains run in parallel

// ---- per-batch barrier state + histogram accumulators (d_ws untouched).
// Each counter/gen on its own 64B line. Counters self-reset (last arriver) and g_gen is a
// generation counter -> graph-replay and rocprof-replay safe. g_hist is parity
// double-buffered: parity = (captured gen)&1; the OTHER buffer is zeroed during phase 1,
// so each execution accumulates into a pre-zeroed buffer with no extra barrier.
__device__ __align__(64) unsigned int g_c1[BMAX * 8 * 16];   // batch b, group g at [(b*8+g)*16]
__device__ __align__(64) unsigned int g_c2[BMAX * 16];
__device__ __align__(64) unsigned int g_gen[BMAX * 16];
__device__ __align__(16) float g_hist[2][BMAX][N_BINS * HSTRIDE];   // 512 KB

// Fused: fine hist -> conv -> 256-bin partial -> device-scope atomicAdd into g_hist ->
// per-batch hierarchical barrier (relaxed RMWs) -> 1KB coherent readback -> scan -> LUT
// -> equalize. Regular launch (graph-capturable). Co-residency capacity-guaranteed:
// 256 blocks, 1/CU needed, each CU fits 4 (8 waves, ~40KB LDS).
__global__ __launch_bounds__(512) void fused_equalize_kernel(const float* __restrict__ x,
                                                             float* __restrict__ out) {
    __shared__ union {
        float cfp[16 * CFP_STRIDE];      // 18.5 KB
        float Tl[QSTRIDE];               // 16 KB
    } A;
    __shared__ union {
        unsigned int lh[QSTRIDE];        // 16 KB
        float ph[256 * 17];              // 17.4 KB
        struct { float wsum[4]; float h0s; } p2;
    } Bu;
    __shared__ float wtE[WPADN];
    __shared__ float cdfnp[288];
    __shared__ float onesp[288];
    __shared__ unsigned int bgen;

    const int b    = blockIdx.y;
    const int s    = blockIdx.x;
    const int tid  = threadIdx.x;
    const int r    = tid & 15;
    const int t    = tid >> 4;       // 0..31
    const int lane = tid & 63;

    // capture this batch's generation BEFORE arrival (uniform across the batch's blocks:
    // gen can only bump after all 64 arrive, and everyone captures before arriving)
    if (tid == 0)
        bgen = __hip_atomic_load(&g_gen[b * 16], __ATOMIC_RELAXED, __HIP_MEMORY_SCOPE_AGENT);

    for (int i = tid; i < QSTRIDE; i += 512) Bu.lh[i] = 0u;
    for (int i = tid; i < 16 * CFP_STRIDE; i += 512) A.cfp[i] = 0.f;
    for (int i = tid; i < WPADN; i += 512) {
        const float d = (float)(i - MWIN) * (1.0f / 4080.f);
        wtE[i] = (i < WTAB) ? __expf(-d * d * (1.0f / (2.0f * TAU * TAU))) : 0.f;
    }
    for (int i = tid; i < 288; i += 512) {
        cdfnp[i] = 0.f;
        onesp[i] = (i >= 13 && i < 269) ? 1.f : 0.f;
    }

    // pixel loads held in registers for the whole kernel (x read exactly once)
    const float4* xb = (const float4*)(x + (size_t)b * HW + (size_t)s * 4096);
    float4 px[2];
    px[0] = xb[tid];
    px[1] = xb[512 + tid];
    __syncthreads();

    const unsigned int mygen = bgen;
    const int par = (int)(mygen & 1u);

    // zero the next execution's buffer (one block per batch; sc1 stores drain by kernel end;
    // stream order serializes executions, so no race with next launch's atomics)
    if (s == 0 && tid < N_BINS)
        __hip_atomic_store(&g_hist[par ^ 1][b][tid * HSTRIDE], 0.f,
                           __ATOMIC_RELAXED, __HIP_MEMORY_SCOPE_AGENT);

    // ---- phase 1a: fine histogram (LDS atomics) ----
#pragma unroll
    for (int i = 0; i < 2; ++i) {
        const float4 v = px[i];
        int q0 = __float2int_rn(v.x * 4080.f);
        int q1 = __float2int_rn(v.y * 4080.f);
        int q2 = __float2int_rn(v.z * 4080.f);
        int q3 = __float2int_rn(v.w * 4080.f);
        q0 = min(max(q0, 0), Q - 1); q1 = min(max(q1, 0), Q - 1);
        q2 = min(max(q2, 0), Q - 1); q3 = min(max(q3, 0), Q - 1);
        atomicAdd(&Bu.lh[q0], 1u); atomicAdd(&Bu.lh[q1], 1u);
        atomicAdd(&Bu.lh[q2], 1u); atomicAdd(&Bu.lh[q3], 1u);
    }
    __syncthreads();

    // scatter fine hist phase-transposed into cfp (pads stay zero)
#pragma unroll
    for (int k = 0; k < 8; ++k) {
        const int q = k * 512 + tid;
        A.cfp[(q & 15) * CFP_STRIDE + (q >> 4) + 13] = (float)Bu.lh[q];
    }
    __syncthreads();

    // ---- phase 1b: register-blocked conv; thread (r,t) computes bins 8t..8t+7, phase r ----
    {
        float creg[34];
        const float* cbase = &A.cfp[r * CFP_STRIDE + 8 * t];
#pragma unroll
        for (int k = 0; k < 34; ++k) creg[k] = cbase[k];
        float acc[8];
#pragma unroll
        for (int uu = 0; uu < 8; ++uu) acc[uu] = 0.f;
#pragma unroll
        for (int p = 0; p < NP; ++p) {
            const float w = wtE[16 * p + r];
#pragma unroll
            for (int uu = 0; uu < 8; ++uu) acc[uu] += w * creg[uu + p];
        }
#pragma unroll
        for (int uu = 0; uu < 8; ++uu) Bu.ph[(8 * t + uu) * 17 + r] = acc[uu];
    }
    __syncthreads();

    // phase-reduce -> device-scope fp atomicAdd into this batch's histogram.
    // Per-bin chain = 64 fire-and-forget RMWs at the LLC; bins on separate lines -> parallel.
    if (tid < N_BINS) {
        float hv = 0.f;
#pragma unroll
        for (int rr = 0; rr < 16; ++rr) hv += Bu.ph[tid * 17 + rr];
        atomicAdd(&g_hist[par][b][tid * HSTRIDE], hv);
    }

    // ---- per-batch barrier (64 arrivals: 8 L1 groups x 8 -> 1 L2 counter) ----
    __syncthreads();   // vmcnt(0) drain: our atomics performed at LLC before arrival
    if (tid == 0) {
        bool master = false;
        unsigned int* c1 = &g_c1[(b * 8 + (s >> 3)) * 16];
        const unsigned int p1 = __hip_atomic_fetch_add(c1, 1u, __ATOMIC_RELAXED,
                                                       __HIP_MEMORY_SCOPE_AGENT);
        if (p1 == 7u) {
            __hip_atomic_store(c1, 0u, __ATOMIC_RELAXED, __HIP_MEMORY_SCOPE_AGENT);
            const unsigned int p2 = __hip_atomic_fetch_add(&g_c2[b * 16], 1u,
                                                           __ATOMIC_RELAXED,
                                                           __HIP_MEMORY_SCOPE_AGENT);
            if (p2 == 7u) {
                __hip_atomic_store(&g_c2[b * 16], 0u, __ATOMIC_RELAXED,
                                   __HIP_MEMORY_SCOPE_AGENT);
                __hip_atomic_fetch_add(&g_gen[b * 16], 1u, __ATOMIC_RELAXED,
                                       __HIP_MEMORY_SCOPE_AGENT);
                master = true;
            }
        }
        if (!master) {
            while (__hip_atomic_load(&g_gen[b * 16], __ATOMIC_RELAXED,
                                     __HIP_MEMORY_SCOPE_AGENT) == mygen) {
                __builtin_amdgcn_s_sleep(1);
            }
        }
        // single acquire per block (one L1/L2 invalidate total, not per spin poll)
        (void)__hip_atomic_load(&g_gen[b * 16], __ATOMIC_ACQUIRE, __HIP_MEMORY_SCOPE_AGENT);
    }
    __syncthreads();

    // ---- phase 2: 1KB coherent readback of the summed histogram + scan + cdf ----
    float val = 0.f, hv = 0.f;
    if (tid < N_BINS) {
        hv = __hip_atomic_load(&g_hist[par][b][tid * HSTRIDE], __ATOMIC_RELAXED,
                               __HIP_MEMORY_SCOPE_AGENT);
        val = hv;
#pragma unroll
        for (int d = 1; d < 64; d <<= 1) {
            const float n = __shfl_up(val, (unsigned)d, 64);
            if (lane >= d) val += n;
        }
        if (lane == 63) Bu.p2.wsum[tid >> 6] = val;
        if (tid == 0) Bu.p2.h0s = hv;
    }
    __syncthreads();
    if (tid < N_BINS) {
        float prefix = 0.f, total = 0.f;
#pragma unroll
        for (int w2 = 0; w2 < 4; ++w2) {
            const float ws = Bu.p2.wsum[w2];
            if (w2 < (tid >> 6)) prefix += ws;
            total += ws;
        }
        val += prefix;
        const float inv  = 1.0f / (total + EPS);
        const float cdf0 = Bu.p2.h0s * inv;
        cdfnp[tid + 13] = (val * inv - cdf0) / (1.0f - cdf0 + EPS);
    }
    __syncthreads();

    // ---- phase 3: output LUT (Tl overlays cfp; cfp dead since phase 1b) ----
    {
        float creg[34], oreg[34];
        const int base = 8 * t;
#pragma unroll
        for (int k = 0; k < 34; ++k) { creg[k] = cdfnp[base + k]; oreg[k] = onesp[base + k]; }
        float acc[8], sw[8];
#pragma unroll
        for (int uu = 0; uu < 8; ++uu) { acc[uu] = 0.f; sw[uu] = 0.f; }
#pragma unroll
        for (int p = 0; p < NP; ++p) {
            const float w = wtE[16 * p + r];
#pragma unroll
            for (int uu = 0; uu < 8; ++uu) {
                const int k = uu - p + 26;   // in [0,34)
                acc[uu] += w * creg[k];
                sw[uu]  += w * oreg[k];
            }
        }
#pragma unroll
        for (int uu = 0; uu < 8; ++uu)
            A.Tl[16 * (8 * t + uu) + r] = acc[uu] / (sw[uu] + EPS);
    }
    __syncthreads();

    // ---- equalize register-held pixels via LUT lerp ----
    float4* ob = (float4*)(out + (size_t)b * HW + (size_t)s * 4096);
#pragma unroll
    for (int i = 0; i < 2; ++i) {
        const float4 v = px[i];
        const float vv[4] = {v.x, v.y, v.z, v.w};
        float res[4];
#pragma unroll
        for (int k2 = 0; k2 < 4; ++k2) {
            const float u = vv[k2] * 4080.f;
            int q = (int)u;
            q = min(max(q, 0), Q - 2);
            const float frac = u - (float)q;
            const float t0 = A.Tl[q], t1 = A.Tl[q + 1];
            res[k2] = fmaf(frac, t1 - t0, t0);
        }
        ob[i * 512 + tid] = make_float4(res[0], res[1], res[2], res[3]);
    }
}

extern "C" void kernel_launch(void* const* d_in, const int* in_sizes, int n_in,
                              void* d_out, int out_size, void* d_ws, size_t ws_size,
                              hipStream_t stream) {
    const float* x = (const float*)d_in[0];
    float* out     = (float*)d_out;
    const int B    = in_sizes[0] / HW;   // = 4

    fused_equalize_kernel<<<dim3(NPART, B), 512, 0, stream>>>(x, out);
}